// Round 4
// baseline (1025.988 us; speedup 1.0000x reference)
//
#include <hip/hip_runtime.h>
#include <math.h>

#define Bsz 2
#define Ssz 2048
#define HIDs 3072
#define NHs 16
#define NKVs 8
#define HDs 256

typedef _Float16 f16;
typedef _Float16 f16x8 __attribute__((ext_vector_type(8)));
typedef _Float16 f16x4 __attribute__((ext_vector_type(4)));
typedef float f32x4 __attribute__((ext_vector_type(4)));

__device__ __forceinline__ void async16(const f16* g, f16* l) {
    __builtin_amdgcn_global_load_lds(
        (const __attribute__((address_space(1))) void*)g,
        (__attribute__((address_space(3))) void*)l, 16, 0, 0);
}

// 16-lane (row) reductions on the VALU pipe via DPP row_ror.
__device__ __forceinline__ float row_max16(float v) {
    int t;
    t = __builtin_amdgcn_mov_dpp(__float_as_int(v), 0x121, 0xf, 0xf, false);
    v = fmaxf(v, __int_as_float(t));
    t = __builtin_amdgcn_mov_dpp(__float_as_int(v), 0x122, 0xf, 0xf, false);
    v = fmaxf(v, __int_as_float(t));
    t = __builtin_amdgcn_mov_dpp(__float_as_int(v), 0x124, 0xf, 0xf, false);
    v = fmaxf(v, __int_as_float(t));
    t = __builtin_amdgcn_mov_dpp(__float_as_int(v), 0x128, 0xf, 0xf, false);
    v = fmaxf(v, __int_as_float(t));
    return v;
}
__device__ __forceinline__ float row_sum16(float v) {
    int t;
    t = __builtin_amdgcn_mov_dpp(__float_as_int(v), 0x121, 0xf, 0xf, false);
    v = v + __int_as_float(t);
    t = __builtin_amdgcn_mov_dpp(__float_as_int(v), 0x122, 0xf, 0xf, false);
    v = v + __int_as_float(t);
    t = __builtin_amdgcn_mov_dpp(__float_as_int(v), 0x124, 0xf, 0xf, false);
    v = v + __int_as_float(t);
    t = __builtin_amdgcn_mov_dpp(__float_as_int(v), 0x128, 0xf, 0xf, false);
    v = v + __int_as_float(t);
    return v;
}

// ---------------- cast fp32 -> fp16 (vectorized x4) ----------------
__global__ void cast_f32_f16_v4(const float4* __restrict__ in, f16x4* __restrict__ out, int n4) {
    int i = blockIdx.x * blockDim.x + threadIdx.x;
    if (i < n4) {
        float4 v = in[i];
        f16x4 r;
        r[0] = (f16)v.x; r[1] = (f16)v.y; r[2] = (f16)v.z; r[3] = (f16)v.w;
        out[i] = r;
    }
}

// ---- NT GEMM (m97 structure): C[M,N] = A[M,K]*B[N,K]^T, f16 in, f32 out ----
__global__ __launch_bounds__(256) void gemm_nt_f16(
    const f16* __restrict__ A, const f16* __restrict__ Bm, float* __restrict__ C,
    int M, int N, int K)
{
    __shared__ __align__(16) f16 As[128 * 32];
    __shared__ __align__(16) f16 Bs[128 * 32];
    const int tid  = threadIdx.x;
    const int wave = tid >> 6, lane = tid & 63;
    const int l15  = lane & 15, quad = lane >> 4;
    const int m0 = blockIdx.y * 128, n0 = blockIdx.x * 128;
    const int wm = (wave >> 1) * 64, wn = (wave & 1) * 64;
    const int srow = wave * 32 + (lane >> 2);
    const int scol = (lane & 3) * 8;

    f32x4 acc[4][4];
    const f32x4 fz = {0.f, 0.f, 0.f, 0.f};
#pragma unroll
    for (int i = 0; i < 4; i++)
#pragma unroll
        for (int j = 0; j < 4; j++) acc[i][j] = fz;

    const f16* Ag0 = A  + (size_t)(m0 + srow) * K + scol;
    const f16* Ag1 = A  + (size_t)(m0 + srow + 16) * K + scol;
    const f16* Bg0 = Bm + (size_t)(n0 + srow) * K + scol;
    const f16* Bg1 = Bm + (size_t)(n0 + srow + 16) * K + scol;
    f16* Al0 = As + (wave * 32) * 32;
    f16* Al1 = As + (wave * 32 + 16) * 32;
    f16* Bl0 = Bs + (wave * 32) * 32;
    f16* Bl1 = Bs + (wave * 32 + 16) * 32;

    for (int k0 = 0; k0 < K; k0 += 32) {
        __syncthreads();
        async16(Ag0 + k0, Al0);
        async16(Ag1 + k0, Al1);
        async16(Bg0 + k0, Bl0);
        async16(Bg1 + k0, Bl1);
        __syncthreads();
        f16x8 af[4], bfr[4];
#pragma unroll
        for (int i = 0; i < 4; i++)
            af[i] = *(const f16x8*)(As + (wm + i * 16 + l15) * 32 + quad * 8);
#pragma unroll
        for (int j = 0; j < 4; j++)
            bfr[j] = *(const f16x8*)(Bs + (wn + j * 16 + l15) * 32 + quad * 8);
#pragma unroll
        for (int i = 0; i < 4; i++)
#pragma unroll
            for (int j = 0; j < 4; j++)
                acc[i][j] = __builtin_amdgcn_mfma_f32_16x16x32_f16(af[i], bfr[j], acc[i][j], 0, 0, 0);
    }
#pragma unroll
    for (int i = 0; i < 4; i++) {
        const int r = m0 + wm + i * 16 + quad * 4;
#pragma unroll
        for (int j = 0; j < 4; j++) {
            const int c = n0 + wn + j * 16 + l15;
#pragma unroll
            for (int rr = 0; rr < 4; rr++)
                C[(size_t)(r + rr) * N + c] = acc[i][j][rr];
        }
    }
}

// ---------------- RoPE for Q (scale 1/sqrt(HD) folded in) ----------------
__global__ void rope_q_kernel(const float* __restrict__ qp, const float* __restrict__ cosb,
                              const float* __restrict__ sinb, f16* __restrict__ qo) {
    const int s = blockIdx.x, h = blockIdx.y, b = blockIdx.z;
    const int d = threadIdx.x;
    const float* row = qp + (size_t)(b * Ssz + s) * (NHs * HDs) + h * HDs;
    float x = row[d];
    float other = (d < 128) ? -row[d + 128] : row[d - 128];
    float val = (x * cosb[s * HDs + d] + other * sinb[s * HDs + d]) * 0.0625f;
    qo[((size_t)(b * NHs + h) * Ssz + s) * HDs + d] = (f16)val;
}

// ---------------- RoPE + BFP4 quantize for K ----------------
__global__ void rope_quant_k_kernel(const float* __restrict__ kp, const float* __restrict__ cosb,
                                    const float* __restrict__ sinb, f16* __restrict__ ko) {
    const int s = blockIdx.x, h = blockIdx.y, b = blockIdx.z;
    const int d = threadIdx.x;
    const float* row = kp + (size_t)(b * Ssz + s) * (NKVs * HDs) + h * HDs;
    float x = row[d];
    float other = (d < 128) ? -row[d + 128] : row[d - 128];
    float val = x * cosb[s * HDs + d] + other * sinb[s * HDs + d];
    __shared__ float red[256];
    red[d] = fabsf(val);
    __syncthreads();
    for (int off = 64; off >= 1; off >>= 1) {
        if ((d & 127) < off) red[d] = fmaxf(red[d], red[d + off]);
        __syncthreads();
    }
    float maxabs = red[d & 128];
    float out;
    if (maxabs > 0.f) {
        int ex;
        frexpf(maxabs, &ex);                 // floor(log2(maxabs)) = ex-1 exactly
        float scale = ldexpf(1.0f, ex - 3);  // 2^(e - (bits-2)), bits=4
        float q = rintf(val / scale);
        q = fminf(7.f, fmaxf(-7.f, q));
        out = q * scale;
    } else out = 0.f;
    ko[((size_t)(b * NKVs + h) * Ssz + s) * HDs + d] = (f16)out;
}

// -------- V: fp32 proj [b][s][kh*256+d] -> f16 Vt [b][kh][d][s] (transposed) --------
__global__ __launch_bounds__(256) void transpose_v_kernel(
    const float* __restrict__ proj, f16* __restrict__ vt)
{
    const int s0 = blockIdx.x * 64, c0 = blockIdx.y * 64, b = blockIdx.z;
    const int tid = threadIdx.x;
    __shared__ f16 T[64 * 72];
    {
        const int r = tid >> 2, cc = (tid & 3) * 16;
        const float* src = proj + (size_t)(b * Ssz + s0 + r) * (NKVs * HDs) + c0 + cc;
        f16 tmp[16];
#pragma unroll
        for (int q4 = 0; q4 < 4; q4++) {
            float4 v = *(const float4*)(src + q4 * 4);
            tmp[q4 * 4 + 0] = (f16)v.x; tmp[q4 * 4 + 1] = (f16)v.y;
            tmp[q4 * 4 + 2] = (f16)v.z; tmp[q4 * 4 + 3] = (f16)v.w;
        }
        *(f16x8*)(T + r * 72 + cc)     = *(f16x8*)(tmp);
        *(f16x8*)(T + r * 72 + cc + 8) = *(f16x8*)(tmp + 8);
    }
    __syncthreads();
    {
        const int d = tid >> 2, sc = (tid & 3) * 16;
        f16 tmp[16];
#pragma unroll
        for (int j = 0; j < 16; j++) tmp[j] = T[(sc + j) * 72 + d];
        const int col = c0 + d;
        const int kh = col >> 8, dd = col & 255;
        f16* dst = vt + ((size_t)(b * NKVs + kh) * HDs + dd) * Ssz + s0 + sc;
        *(f16x8*)(dst)     = *(f16x8*)(tmp);
        *(f16x8*)(dst + 8) = *(f16x8*)(tmp + 8);
    }
}

// ---- flash attention v4: double-buffered K/V LDS, raw s_barrier + vmcnt(8) ----
// 256 thr, 16 Q-rows/wave, Q-tile 64, KV-tile 32, 8 async loads/wave/tile.
__global__ __launch_bounds__(256, 2) void attn_kernel(
    const f16* __restrict__ Q,   // [B][NH][S][HD], pre-scaled by 1/16
    const f16* __restrict__ Kq,  // [B][NKV][S][HD] quantized
    const f16* __restrict__ Vt,  // [B][NKV][HD][S] transposed
    f16* __restrict__ O)         // [B][S][NH*HD]
{
    const int qt = (gridDim.x - 1) - blockIdx.x;   // longest blocks first
    const int h = blockIdx.y, b = blockIdx.z;
    const int kh = h >> 1;
    const int tid = threadIdx.x;
    const int wave = tid >> 6, lane = tid & 63;
    const int l15 = lane & 15, quad = lane >> 4;
    const int wrow = qt * 64 + wave * 16;          // wave's first Q row

    const f16* Qb  = Q  + ((size_t)(b * NHs  + h)  * Ssz) * HDs;
    const f16* Kg  = Kq + ((size_t)(b * NKVs + kh) * Ssz) * HDs;
    const f16* Vtg = Vt + ((size_t)(b * NKVs + kh) * HDs) * Ssz;

    __shared__ __align__(16) f16 Ks[2][32 * 256];  // [kv][d], chunks XOR-swizzled
    __shared__ __align__(16) f16 Vs[2][256 * 32];  // [d][kv]
    __shared__ __align__(16) f16 Pl[4 * 16 * 40];
    f16* Pw = Pl + wave * 16 * 40;

    const int k_r   = lane >> 5;
    const int k_cs  = (lane & 31) ^ (k_r << 2);
    const int v_r   = lane >> 2;
    const int v_c   = (lane & 3) * 8;

    f16x8 qf[8];
    {
        const f16* qrow = Qb + (size_t)(wrow + l15) * HDs + quad * 8;
#pragma unroll
        for (int ks = 0; ks < 8; ks++)
            qf[ks] = *(const f16x8*)(qrow + ks * 32);
    }

    const f32x4 fz = {0.f, 0.f, 0.f, 0.f};
    f32x4 accO[16];
#pragma unroll
    for (int jn = 0; jn < 16; jn++) accO[jn] = fz;
    float mrow[4], lpart[4];
#pragma unroll
    for (int r = 0; r < 4; r++) { mrow[r] = -1e30f; lpart[r] = 0.f; }

    const int nk = 2 * qt + 2;
    const int wave_max_row = wrow + 15;

    // ---- stage tile `kt` into buffer `bi`: exactly 8 async loads per wave ----
    auto stage = [&](int kt, int bi) {
        const int kvb = kt * 32;
        f16* KsB = &Ks[bi][0];
        f16* VsB = &Vs[bi][0];
#pragma unroll
        for (int t = 0; t < 4; t++) {
            const int r2 = wave * 8 + t * 2;
            async16(Kg + (size_t)(kvb + r2 + k_r) * 256 + k_cs * 8, KsB + r2 * 256);
        }
#pragma unroll
        for (int t = 0; t < 4; t++) {
            const int d0 = wave * 64 + t * 16;
            async16(Vtg + (size_t)(d0 + v_r) * Ssz + kvb + v_c, VsB + d0 * 32);
        }
    };

    stage(0, 0);
    for (int kt = 0; kt < nk; kt++) {
        const int cur = kt & 1;
        if (kt + 1 < nk) {
            if (kt >= 1) __builtin_amdgcn_s_barrier();   // all waves done reading buf cur^1
            stage(kt + 1, cur ^ 1);                      // async prefetch
            __builtin_amdgcn_s_waitcnt(0x0F78);          // vmcnt(8): tile kt landed in LDS
        } else {
            __builtin_amdgcn_s_waitcnt(0x0F70);          // vmcnt(0): last tile landed
        }
        __builtin_amdgcn_s_barrier();                    // tile kt visible to all waves

        const int kvb = kt * 32;
        if (kvb <= wave_max_row) {
            const f16* KsB = &Ks[cur][0];
            const f16* VsB = &Vs[cur][0];
            f32x4 sv0 = fz, sv1 = fz;
            const int sw0 = (l15 & 1) << 2;
#pragma unroll
            for (int ks = 0; ks < 8; ks++) {
                const int cpos = ((ks * 4 + quad) ^ sw0) * 8;
                f16x8 kf0 = *(const f16x8*)(KsB + l15 * 256 + cpos);
                f16x8 kf1 = *(const f16x8*)(KsB + (16 + l15) * 256 + cpos);
                sv0 = __builtin_amdgcn_mfma_f32_16x16x32_f16(qf[ks], kf0, sv0, 0, 0, 0);
                sv1 = __builtin_amdgcn_mfma_f32_16x16x32_f16(qf[ks], kf1, sv1, 0, 0, 0);
            }
            float aup[4];
            bool need = false;
#pragma unroll
            for (int r = 0; r < 4; r++) {
                float s0 = sv0[r], s1 = sv1[r];
                const int row = wrow + quad * 4 + r;
                if (kvb + 31 > row) {
                    if (kvb + l15 > row)      s0 = -1e30f;
                    if (kvb + 16 + l15 > row) s1 = -1e30f;
                }
                float rmax = row_max16(fmaxf(s0, s1));
                float mold = mrow[r];
                float mnew = fmaxf(mold, rmax);
                aup[r] = __expf(mold - mnew);
                need = need || (mnew > mold);
                float p0 = __expf(s0 - mnew);
                float p1 = __expf(s1 - mnew);
                lpart[r] = lpart[r] * aup[r] + (p0 + p1);
                mrow[r] = mnew;
                Pw[(quad * 4 + r) * 40 + l15]      = (f16)p0;
                Pw[(quad * 4 + r) * 40 + 16 + l15] = (f16)p1;
            }
            if (__any(need)) {
#pragma unroll
                for (int jn = 0; jn < 16; jn++) {
                    f32x4 t = accO[jn];
                    t[0] *= aup[0]; t[1] *= aup[1]; t[2] *= aup[2]; t[3] *= aup[3];
                    accO[jn] = t;
                }
            }
            // P (C-layout) -> A-layout via same-wave LDS round trip
            f16x8 pf = *(const f16x8*)(Pw + l15 * 40 + quad * 8);
#pragma unroll
            for (int jn = 0; jn < 16; jn++) {
                f16x8 vf = *(const f16x8*)(VsB + (jn * 16 + l15) * 32 + quad * 8);
                accO[jn] = __builtin_amdgcn_mfma_f32_16x16x32_f16(pf, vf, accO[jn], 0, 0, 0);
            }
        }
    }
#pragma unroll
    for (int r = 0; r < 4; r++) {
        const int row = wrow + quad * 4 + r;
        const float inv = 1.0f / row_sum16(lpart[r]);
        f16* orow = O + ((size_t)(b * Ssz) + row) * (NHs * HDs) + h * HDs;
#pragma unroll
        for (int jn = 0; jn < 16; jn++)
            orow[jn * 16 + l15] = (f16)(accO[jn][r] * inv);
    }
}

// ---------------- launcher ----------------
extern "C" void kernel_launch(void* const* d_in, const int* in_sizes, int n_in,
                              void* d_out, int out_size, void* d_ws, size_t ws_size,
                              hipStream_t stream) {
    const float* hs   = (const float*)d_in[0];
    const float* Wq   = (const float*)d_in[1];
    const float* Wk   = (const float*)d_in[2];
    const float* Wv   = (const float*)d_in[3];
    const float* Wo   = (const float*)d_in[4];
    const float* cosb = (const float*)d_in[5];
    const float* sinb = (const float*)d_in[6];
    float* out = (float*)d_out;

    char* ws = (char*)d_ws;
    f16*   hs_h = (f16*)(ws);                    // 25165824 B
    f16*   w_h  = (f16*)(ws + 25165824);         // 25165824 B (reused per weight)
    float* proj = (float*)(ws + 50331648);       // 67108864 B (reused)
    f16*   q_h  = (f16*)(ws + 117440512);        // 33554432 B
    f16*   k_h  = (f16*)(ws + 150994944);        // 16777216 B
    f16*   vt_h = (f16*)(ws + 167772160);        // 16777216 B
    f16*   ao_h = (f16*)proj;                    // attn output reuses proj region

    int n4;
    n4 = (Bsz * Ssz * HIDs) / 4;
    cast_f32_f16_v4<<<n4 / 256, 256, 0, stream>>>((const float4*)hs, (f16x4*)hs_h, n4);
    // Q projection
    n4 = (NHs * HDs * HIDs) / 4;
    cast_f32_f16_v4<<<n4 / 256, 256, 0, stream>>>((const float4*)Wq, (f16x4*)w_h, n4);
    gemm_nt_f16<<<dim3(4096 / 128, 4096 / 128), 256, 0, stream>>>(hs_h, w_h, proj, 4096, 4096, 3072);
    rope_q_kernel<<<dim3(Ssz, NHs, Bsz), 256, 0, stream>>>(proj, cosb, sinb, q_h);
    // K projection + quantize
    n4 = (NKVs * HDs * HIDs) / 4;
    cast_f32_f16_v4<<<n4 / 256, 256, 0, stream>>>((const float4*)Wk, (f16x4*)w_h, n4);
    gemm_nt_f16<<<dim3(2048 / 128, 4096 / 128), 256, 0, stream>>>(hs_h, w_h, proj, 4096, 2048, 3072);
    rope_quant_k_kernel<<<dim3(Ssz, NKVs, Bsz), 256, 0, stream>>>(proj, cosb, sinb, k_h);
    // V projection + transpose
    n4 = (NKVs * HDs * HIDs) / 4;
    cast_f32_f16_v4<<<n4 / 256, 256, 0, stream>>>((const float4*)Wv, (f16x4*)w_h, n4);
    gemm_nt_f16<<<dim3(2048 / 128, 4096 / 128), 256, 0, stream>>>(hs_h, w_h, proj, 4096, 2048, 3072);
    transpose_v_kernel<<<dim3(Ssz / 64, (NKVs * HDs) / 64, Bsz), 256, 0, stream>>>(proj, vt_h);
    // attention: Q-tile 64 -> 1024 blocks, longest-first
    attn_kernel<<<dim3(Ssz / 64, NHs, Bsz), 256, 0, stream>>>(q_h, k_h, vt_h, ao_h);
    // output projection -> d_out
    n4 = (HIDs * NHs * HDs) / 4;
    cast_f32_f16_v4<<<n4 / 256, 256, 0, stream>>>((const float4*)Wo, (f16x4*)w_h, n4);
    gemm_nt_f16<<<dim3(3072 / 128, 4096 / 128), 256, 0, stream>>>(ao_h, w_h, out, 4096, 3072, 4096);
}

// Round 5
// 1003.222 us; speedup vs baseline: 1.0227x; 1.0227x over previous
//
#include <hip/hip_runtime.h>
#include <math.h>

#define Bsz 2
#define Ssz 2048
#define HIDs 3072
#define NHs 16
#define NKVs 8
#define HDs 256

typedef _Float16 f16;
typedef _Float16 f16x8 __attribute__((ext_vector_type(8)));
typedef _Float16 f16x4 __attribute__((ext_vector_type(4)));
typedef float f32x4 __attribute__((ext_vector_type(4)));

__device__ __forceinline__ void async16(const f16* g, f16* l) {
    __builtin_amdgcn_global_load_lds(
        (const __attribute__((address_space(1))) void*)g,
        (__attribute__((address_space(3))) void*)l, 16, 0, 0);
}

// 16-lane (quad-row) reductions on the VALU pipe via DPP row_ror.
__device__ __forceinline__ float row_max16(float v) {
    int t;
    t = __builtin_amdgcn_mov_dpp(__float_as_int(v), 0x121, 0xf, 0xf, false);
    v = fmaxf(v, __int_as_float(t));
    t = __builtin_amdgcn_mov_dpp(__float_as_int(v), 0x122, 0xf, 0xf, false);
    v = fmaxf(v, __int_as_float(t));
    t = __builtin_amdgcn_mov_dpp(__float_as_int(v), 0x124, 0xf, 0xf, false);
    v = fmaxf(v, __int_as_float(t));
    t = __builtin_amdgcn_mov_dpp(__float_as_int(v), 0x128, 0xf, 0xf, false);
    v = fmaxf(v, __int_as_float(t));
    return v;
}
__device__ __forceinline__ float row_sum16(float v) {
    int t;
    t = __builtin_amdgcn_mov_dpp(__float_as_int(v), 0x121, 0xf, 0xf, false);
    v = v + __int_as_float(t);
    t = __builtin_amdgcn_mov_dpp(__float_as_int(v), 0x122, 0xf, 0xf, false);
    v = v + __int_as_float(t);
    t = __builtin_amdgcn_mov_dpp(__float_as_int(v), 0x124, 0xf, 0xf, false);
    v = v + __int_as_float(t);
    t = __builtin_amdgcn_mov_dpp(__float_as_int(v), 0x128, 0xf, 0xf, false);
    v = v + __int_as_float(t);
    return v;
}

// ---------------- fused cast fp32 -> fp16 for all 5 inputs (1 launch) ----------------
#define N4_HS  3145728
#define N4_WQ  3145728
#define N4_WK  1572864
#define N4_WV  1572864
#define N4_WO  3145728
#define N4_TOT (N4_HS + N4_WQ + N4_WK + N4_WV + N4_WO)

__global__ void cast_all_kernel(const float4* __restrict__ hs, const float4* __restrict__ wq,
                                const float4* __restrict__ wk, const float4* __restrict__ wv,
                                const float4* __restrict__ wo,
                                f16x4* __restrict__ hs_h, f16x4* __restrict__ wq_h,
                                f16x4* __restrict__ wk_h, f16x4* __restrict__ wv_h,
                                f16x4* __restrict__ wo_h) {
    int i = blockIdx.x * blockDim.x + threadIdx.x;
    const float4* src; f16x4* dst; int off;
    if (i < N4_HS)                       { src = hs; dst = hs_h; off = i; }
    else if (i < N4_HS + N4_WQ)          { src = wq; dst = wq_h; off = i - N4_HS; }
    else if (i < N4_HS + N4_WQ + N4_WK)  { src = wk; dst = wk_h; off = i - (N4_HS + N4_WQ); }
    else if (i < N4_TOT - N4_WO)         { src = wv; dst = wv_h; off = i - (N4_HS + N4_WQ + N4_WK); }
    else                                 { src = wo; dst = wo_h; off = i - (N4_TOT - N4_WO); }
    float4 v = src[off];
    f16x4 r;
    r[0] = (f16)v.x; r[1] = (f16)v.y; r[2] = (f16)v.z; r[3] = (f16)v.w;
    dst[off] = r;
}

// ---- NT GEMM (m97 structure): C[M,N] = A[M,K]*B[N,K]^T, f16 in, f32 out ----
__global__ __launch_bounds__(256) void gemm_nt_f16(
    const f16* __restrict__ A, const f16* __restrict__ Bm, float* __restrict__ C,
    int M, int N, int K)
{
    __shared__ __align__(16) f16 As[128 * 32];
    __shared__ __align__(16) f16 Bs[128 * 32];
    const int tid  = threadIdx.x;
    const int wave = tid >> 6, lane = tid & 63;
    const int l15  = lane & 15, quad = lane >> 4;
    const int m0 = blockIdx.y * 128, n0 = blockIdx.x * 128;
    const int wm = (wave >> 1) * 64, wn = (wave & 1) * 64;
    const int srow = wave * 32 + (lane >> 2);
    const int scol = (lane & 3) * 8;

    f32x4 acc[4][4];
    const f32x4 fz = {0.f, 0.f, 0.f, 0.f};
#pragma unroll
    for (int i = 0; i < 4; i++)
#pragma unroll
        for (int j = 0; j < 4; j++) acc[i][j] = fz;

    const f16* Ag0 = A  + (size_t)(m0 + srow) * K + scol;
    const f16* Ag1 = A  + (size_t)(m0 + srow + 16) * K + scol;
    const f16* Bg0 = Bm + (size_t)(n0 + srow) * K + scol;
    const f16* Bg1 = Bm + (size_t)(n0 + srow + 16) * K + scol;
    f16* Al0 = As + (wave * 32) * 32;
    f16* Al1 = As + (wave * 32 + 16) * 32;
    f16* Bl0 = Bs + (wave * 32) * 32;
    f16* Bl1 = Bs + (wave * 32 + 16) * 32;

    for (int k0 = 0; k0 < K; k0 += 32) {
        __syncthreads();
        async16(Ag0 + k0, Al0);
        async16(Ag1 + k0, Al1);
        async16(Bg0 + k0, Bl0);
        async16(Bg1 + k0, Bl1);
        __syncthreads();
        f16x8 af[4], bfr[4];
#pragma unroll
        for (int i = 0; i < 4; i++)
            af[i] = *(const f16x8*)(As + (wm + i * 16 + l15) * 32 + quad * 8);
#pragma unroll
        for (int j = 0; j < 4; j++)
            bfr[j] = *(const f16x8*)(Bs + (wn + j * 16 + l15) * 32 + quad * 8);
#pragma unroll
        for (int i = 0; i < 4; i++)
#pragma unroll
            for (int j = 0; j < 4; j++)
                acc[i][j] = __builtin_amdgcn_mfma_f32_16x16x32_f16(af[i], bfr[j], acc[i][j], 0, 0, 0);
    }
#pragma unroll
    for (int i = 0; i < 4; i++) {
        const int r = m0 + wm + i * 16 + quad * 4;
#pragma unroll
        for (int j = 0; j < 4; j++) {
            const int c = n0 + wn + j * 16 + l15;
#pragma unroll
            for (int rr = 0; rr < 4; rr++)
                C[(size_t)(r + rr) * N + c] = acc[i][j][rr];
        }
    }
}

// ---------------- RoPE for Q (scale 1/sqrt(HD) folded in) ----------------
__global__ void rope_q_kernel(const float* __restrict__ qp, const float* __restrict__ cosb,
                              const float* __restrict__ sinb, f16* __restrict__ qo) {
    const int s = blockIdx.x, h = blockIdx.y, b = blockIdx.z;
    const int d = threadIdx.x;
    const float* row = qp + (size_t)(b * Ssz + s) * (NHs * HDs) + h * HDs;
    float x = row[d];
    float other = (d < 128) ? -row[d + 128] : row[d - 128];
    float val = (x * cosb[s * HDs + d] + other * sinb[s * HDs + d]) * 0.0625f;
    qo[((size_t)(b * NHs + h) * Ssz + s) * HDs + d] = (f16)val;
}

// ---------------- RoPE + BFP4 quantize for K ----------------
__global__ void rope_quant_k_kernel(const float* __restrict__ kp, const float* __restrict__ cosb,
                                    const float* __restrict__ sinb, f16* __restrict__ ko) {
    const int s = blockIdx.x, h = blockIdx.y, b = blockIdx.z;
    const int d = threadIdx.x;
    const float* row = kp + (size_t)(b * Ssz + s) * (NKVs * HDs) + h * HDs;
    float x = row[d];
    float other = (d < 128) ? -row[d + 128] : row[d - 128];
    float val = x * cosb[s * HDs + d] + other * sinb[s * HDs + d];
    __shared__ float red[256];
    red[d] = fabsf(val);
    __syncthreads();
    for (int off = 64; off >= 1; off >>= 1) {
        if ((d & 127) < off) red[d] = fmaxf(red[d], red[d + off]);
        __syncthreads();
    }
    float maxabs = red[d & 128];
    float out;
    if (maxabs > 0.f) {
        int ex;
        frexpf(maxabs, &ex);                 // floor(log2(maxabs)) = ex-1 exactly
        float scale = ldexpf(1.0f, ex - 3);  // 2^(e - (bits-2)), bits=4
        float q = rintf(val / scale);
        q = fminf(7.f, fmaxf(-7.f, q));
        out = q * scale;
    } else out = 0.f;
    ko[((size_t)(b * NKVs + h) * Ssz + s) * HDs + d] = (f16)out;
}

// -------- V: fp32 proj [b][s][kh*256+d] -> f16 Vt [b][kh][d][s] (transposed) --------
__global__ __launch_bounds__(256) void transpose_v_kernel(
    const float* __restrict__ proj, f16* __restrict__ vt)
{
    const int s0 = blockIdx.x * 64, c0 = blockIdx.y * 64, b = blockIdx.z;
    const int tid = threadIdx.x;
    __shared__ f16 T[64 * 72];
    {
        const int r = tid >> 2, cc = (tid & 3) * 16;
        const float* src = proj + (size_t)(b * Ssz + s0 + r) * (NKVs * HDs) + c0 + cc;
        f16 tmp[16];
#pragma unroll
        for (int q4 = 0; q4 < 4; q4++) {
            float4 v = *(const float4*)(src + q4 * 4);
            tmp[q4 * 4 + 0] = (f16)v.x; tmp[q4 * 4 + 1] = (f16)v.y;
            tmp[q4 * 4 + 2] = (f16)v.z; tmp[q4 * 4 + 3] = (f16)v.w;
        }
        *(f16x8*)(T + r * 72 + cc)     = *(f16x8*)(tmp);
        *(f16x8*)(T + r * 72 + cc + 8) = *(f16x8*)(tmp + 8);
    }
    __syncthreads();
    {
        const int d = tid >> 2, sc = (tid & 3) * 16;
        f16 tmp[16];
#pragma unroll
        for (int j = 0; j < 16; j++) tmp[j] = T[(sc + j) * 72 + d];
        const int col = c0 + d;
        const int kh = col >> 8, dd = col & 255;
        f16* dst = vt + ((size_t)(b * NKVs + kh) * HDs + dd) * Ssz + s0 + sc;
        *(f16x8*)(dst)     = *(f16x8*)(tmp);
        *(f16x8*)(dst + 8) = *(f16x8*)(tmp + 8);
    }
}

// ---- flash attention v5: 256 thr, 32 Q-rows/wave (2 subtiles), Q-tile 128 ----
// Single-buffered K/V LDS (43 KB) -> 2 blocks/CU; launch_bounds(256,2) caps
// regs at 256/wave (accO 128 AGPR + qf 64 + temps).
__global__ __launch_bounds__(256, 2) void attn_kernel(
    const f16* __restrict__ Q,   // [B][NH][S][HD], pre-scaled by 1/16
    const f16* __restrict__ Kq,  // [B][NKV][S][HD] quantized
    const f16* __restrict__ Vt,  // [B][NKV][HD][S] transposed
    f16* __restrict__ O)         // [B][S][NH*HD]
{
    const int qt = (gridDim.x - 1) - blockIdx.x;   // longest blocks first
    const int h = blockIdx.y, b = blockIdx.z;
    const int kh = h >> 1;
    const int tid = threadIdx.x;
    const int wave = tid >> 6, lane = tid & 63;
    const int l15 = lane & 15, quad = lane >> 4;
    const int wrow = qt * 128 + wave * 32;         // wave's first Q row (32 rows)

    const f16* Qb  = Q  + ((size_t)(b * NHs  + h)  * Ssz) * HDs;
    const f16* Kg  = Kq + ((size_t)(b * NKVs + kh) * Ssz) * HDs;
    const f16* Vtg = Vt + ((size_t)(b * NKVs + kh) * HDs) * Ssz;

    __shared__ __align__(16) f16 Ks[32 * 256];   // [kv][d], chunks XOR-swizzled
    __shared__ __align__(16) f16 Vs[256 * 32];   // [d][kv], chunks XOR-swizzled
    __shared__ __align__(16) f16 Pl[4 * 32 * 40];
    f16* Pw = Pl + wave * 32 * 40;

    const int k_r  = lane >> 5;
    const int k_cs = (lane & 31) ^ (k_r << 2);
    const int v_r  = lane >> 2;                        // d-row within 16-group
    const int v_cs = ((lane & 3) ^ (v_r & 3)) * 8;     // swizzled global kv-chunk

    f16x8 qf0[8], qf1[8];
    {
        const f16* qrow0 = Qb + (size_t)(wrow + l15) * HDs + quad * 8;
        const f16* qrow1 = qrow0 + (size_t)16 * HDs;
#pragma unroll
        for (int ks = 0; ks < 8; ks++) {
            qf0[ks] = *(const f16x8*)(qrow0 + ks * 32);
            qf1[ks] = *(const f16x8*)(qrow1 + ks * 32);
        }
    }

    const f32x4 fz = {0.f, 0.f, 0.f, 0.f};
    f32x4 accO0[16], accO1[16];
#pragma unroll
    for (int jn = 0; jn < 16; jn++) { accO0[jn] = fz; accO1[jn] = fz; }
    float mrow0[4], mrow1[4], lp0[4], lp1[4];
#pragma unroll
    for (int r = 0; r < 4; r++) { mrow0[r] = -1e30f; mrow1[r] = -1e30f; lp0[r] = 0.f; lp1[r] = 0.f; }

    const int nk = 4 * qt + 4;
    const int wave_max_row = wrow + 31;

    for (int kt = 0; kt < nk; kt++) {
        const int kvb = kt * 32;
        __syncthreads();   // previous tile fully consumed
#pragma unroll
        for (int t = 0; t < 4; t++) {
            const int r2 = wave * 8 + t * 2;
            async16(Kg + (size_t)(kvb + r2 + k_r) * 256 + k_cs * 8, Ks + r2 * 256);
        }
#pragma unroll
        for (int t = 0; t < 4; t++) {
            const int d0 = wave * 64 + t * 16;
            async16(Vtg + (size_t)(d0 + v_r) * Ssz + kvb + v_cs, Vs + d0 * 32);
        }
        __syncthreads();   // drains vmcnt(0): tile visible

        if (kvb <= wave_max_row) {
            f32x4 s00 = fz, s01 = fz, s10 = fz, s11 = fz;
            const int sw0 = (l15 & 1) << 2;
#pragma unroll
            for (int ks = 0; ks < 8; ks++) {
                const int cpos = ((ks * 4 + quad) ^ sw0) * 8;
                f16x8 kf0 = *(const f16x8*)(Ks + l15 * 256 + cpos);
                f16x8 kf1 = *(const f16x8*)(Ks + (16 + l15) * 256 + cpos);
                s00 = __builtin_amdgcn_mfma_f32_16x16x32_f16(qf0[ks], kf0, s00, 0, 0, 0);
                s01 = __builtin_amdgcn_mfma_f32_16x16x32_f16(qf0[ks], kf1, s01, 0, 0, 0);
                s10 = __builtin_amdgcn_mfma_f32_16x16x32_f16(qf1[ks], kf0, s10, 0, 0, 0);
                s11 = __builtin_amdgcn_mfma_f32_16x16x32_f16(qf1[ks], kf1, s11, 0, 0, 0);
            }
            float a0[4], a1[4];
            bool need = false;
            const bool diag = (kvb + 31 > wrow);   // any masking in this tile
#pragma unroll
            for (int r = 0; r < 4; r++) {
                // subtile 0: rows wrow + quad*4 + r
                float x0 = s00[r], x1 = s01[r];
                const int row0 = wrow + quad * 4 + r;
                if (diag) {
                    if (kvb + l15 > row0)      x0 = -1e30f;
                    if (kvb + 16 + l15 > row0) x1 = -1e30f;
                }
                float rmax = row_max16(fmaxf(x0, x1));
                float mold = mrow0[r];
                float mnew = fmaxf(mold, rmax);
                a0[r] = __expf(mold - mnew);
                need = need || (mnew > mold);
                float p0 = __expf(x0 - mnew);
                float p1 = __expf(x1 - mnew);
                lp0[r] = lp0[r] * a0[r] + (p0 + p1);
                mrow0[r] = mnew;
                Pw[(quad * 4 + r) * 40 + l15]      = (f16)p0;
                Pw[(quad * 4 + r) * 40 + 16 + l15] = (f16)p1;
                // subtile 1: rows wrow + 16 + quad*4 + r
                float y0 = s10[r], y1 = s11[r];
                const int row1 = row0 + 16;
                if (diag) {
                    if (kvb + l15 > row1)      y0 = -1e30f;
                    if (kvb + 16 + l15 > row1) y1 = -1e30f;
                }
                float rmax1 = row_max16(fmaxf(y0, y1));
                float mold1 = mrow1[r];
                float mnew1 = fmaxf(mold1, rmax1);
                a1[r] = __expf(mold1 - mnew1);
                need = need || (mnew1 > mold1);
                float q0 = __expf(y0 - mnew1);
                float q1 = __expf(y1 - mnew1);
                lp1[r] = lp1[r] * a1[r] + (q0 + q1);
                mrow1[r] = mnew1;
                Pw[(16 + quad * 4 + r) * 40 + l15]      = (f16)q0;
                Pw[(16 + quad * 4 + r) * 40 + 16 + l15] = (f16)q1;
            }
            if (__any(need)) {
#pragma unroll
                for (int jn = 0; jn < 16; jn++) {
                    f32x4 t0 = accO0[jn], t1 = accO1[jn];
                    t0[0] *= a0[0]; t0[1] *= a0[1]; t0[2] *= a0[2]; t0[3] *= a0[3];
                    t1[0] *= a1[0]; t1[1] *= a1[1]; t1[2] *= a1[2]; t1[3] *= a1[3];
                    accO0[jn] = t0; accO1[jn] = t1;
                }
            }
            // P (C-layout) -> A-layout via same-wave LDS round trip
            f16x8 pf0 = *(const f16x8*)(Pw + l15 * 40 + quad * 8);
            f16x8 pf1 = *(const f16x8*)(Pw + (16 + l15) * 40 + quad * 8);
#pragma unroll
            for (int jn = 0; jn < 16; jn++) {
                f16x8 vf = *(const f16x8*)(Vs + (jn * 16 + l15) * 32 + ((quad ^ (l15 & 3))) * 8);
                accO0[jn] = __builtin_amdgcn_mfma_f32_16x16x32_f16(pf0, vf, accO0[jn], 0, 0, 0);
                accO1[jn] = __builtin_amdgcn_mfma_f32_16x16x32_f16(pf1, vf, accO1[jn], 0, 0, 0);
            }
        }
    }
#pragma unroll
    for (int r = 0; r < 4; r++) {
        const int row0 = wrow + quad * 4 + r;
        const float inv0 = 1.0f / row_sum16(lp0[r]);
        f16* orow0 = O + ((size_t)(b * Ssz) + row0) * (NHs * HDs) + h * HDs;
#pragma unroll
        for (int jn = 0; jn < 16; jn++)
            orow0[jn * 16 + l15] = (f16)(accO0[jn][r] * inv0);
        const int row1 = row0 + 16;
        const float inv1 = 1.0f / row_sum16(lp1[r]);
        f16* orow1 = O + ((size_t)(b * Ssz) + row1) * (NHs * HDs) + h * HDs;
#pragma unroll
        for (int jn = 0; jn < 16; jn++)
            orow1[jn * 16 + l15] = (f16)(accO1[jn][r] * inv1);
    }
}

// ---------------- launcher ----------------
extern "C" void kernel_launch(void* const* d_in, const int* in_sizes, int n_in,
                              void* d_out, int out_size, void* d_ws, size_t ws_size,
                              hipStream_t stream) {
    const float* hs   = (const float*)d_in[0];
    const float* Wq   = (const float*)d_in[1];
    const float* Wk   = (const float*)d_in[2];
    const float* Wv   = (const float*)d_in[3];
    const float* Wo   = (const float*)d_in[4];
    const float* cosb = (const float*)d_in[5];
    const float* sinb = (const float*)d_in[6];
    float* out = (float*)d_out;

    char* ws = (char*)d_ws;
    f16*   hs_h = (f16*)(ws);                    // 25165824 B  (hidden f16)
    f16*   wo_h = (f16*)(ws + 25165824);         // 25165824 B  (Wo f16)
    float* proj = (float*)(ws + 50331648);       // 67108864 B  (reused)
    f16*   q_h  = (f16*)(ws + 117440512);        // 33554432 B  (Wq f16 first, then roped Q)
    f16*   k_h  = (f16*)(ws + 150994944);        // 16777216 B  (Wk f16 first, then quant K)
    f16*   vt_h = (f16*)(ws + 167772160);        // 16777216 B  (Wv f16 first, then Vt)
    f16*   ao_h = (f16*)proj;                    // attn output reuses proj region

    // one fused cast: hs->hs_h, Wq->q_h, Wk->k_h, Wv->vt_h, Wo->wo_h
    cast_all_kernel<<<N4_TOT / 256, 256, 0, stream>>>(
        (const float4*)hs, (const float4*)Wq, (const float4*)Wk,
        (const float4*)Wv, (const float4*)Wo,
        (f16x4*)hs_h, (f16x4*)q_h, (f16x4*)k_h, (f16x4*)vt_h, (f16x4*)wo_h);

    // Q projection (B = Wq living in q_h region; rope then overwrites q_h)
    gemm_nt_f16<<<dim3(4096 / 128, 4096 / 128), 256, 0, stream>>>(hs_h, q_h, proj, 4096, 4096, 3072);
    rope_q_kernel<<<dim3(Ssz, NHs, Bsz), 256, 0, stream>>>(proj, cosb, sinb, q_h);
    // K projection + quantize (B = Wk in k_h; then overwritten)
    gemm_nt_f16<<<dim3(2048 / 128, 4096 / 128), 256, 0, stream>>>(hs_h, k_h, proj, 4096, 2048, 3072);
    rope_quant_k_kernel<<<dim3(Ssz, NKVs, Bsz), 256, 0, stream>>>(proj, cosb, sinb, k_h);
    // V projection + transpose (B = Wv in vt_h; then overwritten)
    gemm_nt_f16<<<dim3(2048 / 128, 4096 / 128), 256, 0, stream>>>(hs_h, vt_h, proj, 4096, 2048, 3072);
    transpose_v_kernel<<<dim3(Ssz / 64, (NKVs * HDs) / 64, Bsz), 256, 0, stream>>>(proj, vt_h);
    // attention: Q-tile 128 -> 512 blocks, longest-first
    attn_kernel<<<dim3(Ssz / 128, NHs, Bsz), 256, 0, stream>>>(q_h, k_h, vt_h, ao_h);
    // output projection -> d_out
    gemm_nt_f16<<<dim3(3072 / 128, 4096 / 128), 256, 0, stream>>>(ao_h, wo_h, out, 4096, 3072, 4096);
}